// Round 10
// baseline (441.300 us; speedup 1.0000x reference)
//
#include <hip/hip_runtime.h>

// ManualCrossAttention: B=32,P=512,S=1024,E=512,H=8,D=64
// cvt weights (pre-swizzled) -> mask pack (d_out scratch) -> Q/K/V swapped-projection GEMMs
// (A=W f16 GLD16 double-buffered, B=act f32 T14 issue-early/write-late, packed stores)
// -> flash attn (swapped QK^T, reg softmax, T14 prefetch, T13 defer-max, T5 setprio) -> out proj.
#define B_  32
#define P_  512
#define S_  1024
#define E_  512
#define H_  8
#define D_  64

typedef unsigned int uint32;
typedef unsigned short u16;
typedef __attribute__((ext_vector_type(8))) _Float16 half8;
typedef __attribute__((ext_vector_type(2))) __fp16 fp16x2;
typedef __attribute__((ext_vector_type(4))) float f32x4;
typedef __attribute__((ext_vector_type(2))) uint32 u32x2;
typedef __attribute__((ext_vector_type(4))) uint32 u32x4;

__device__ __forceinline__ u16 f2h_bits(float f){
  _Float16 h = (_Float16)f;
  union { _Float16 h; u16 u; } cv; cv.h = h; return cv.u;
}
__device__ __forceinline__ uint32 pk16(float a, float b){
  union { fp16x2 h; uint32 u; } cv;
  cv.h = __builtin_amdgcn_cvt_pkrtz(a, b);
  return cv.u;
}
__device__ __forceinline__ half8 cvt8(f32x4 a, f32x4 b){
  half8 h;
  h[0]=(_Float16)a[0]; h[1]=(_Float16)a[1]; h[2]=(_Float16)a[2]; h[3]=(_Float16)a[3];
  h[4]=(_Float16)b[0]; h[5]=(_Float16)b[1]; h[6]=(_Float16)b[2]; h[7]=(_Float16)b[3];
  return h;
}
__device__ __forceinline__ f32x4 mfma16(half8 a, half8 b, f32x4 c){
  return __builtin_amdgcn_mfma_f32_16x16x32_f16(a, b, c, 0, 0, 0);
}
// swizzled LDS index (u16 elems, 64/row): col c of row -> c ^ ((row&7)<<3)
__device__ __forceinline__ int swz(int row, int col){ return row*64 + (col ^ ((row & 7) << 3)); }
// async global->LDS, 16B per lane. LDS dest must be wave-uniform base + lane*16.
#define GLD16(ldsp, gp) __builtin_amdgcn_global_load_lds( \
    (const __attribute__((address_space(1))) void*)(gp), \
    (__attribute__((address_space(3))) void*)(ldsp), 16, 0, 0)

// ---------------- weight conversion; Wq/Wk/Wv stored pre-swizzled (for GLD16 + swz reads) ----
__global__ void cvt_w_kernel(const float* __restrict__ w0, const float* __restrict__ w1,
                             const float* __restrict__ w2, const float* __restrict__ w3,
                             u16* __restrict__ out){
  int i = blockIdx.x * 256 + threadIdx.x;          // 131072 threads, 8 elems each
  int region = i >> 15;                            // 0..3 (Wq,Wk,Wv swz; Wo linear)
  int off = (i & 32767) * 8;
  const float* s = (region == 0) ? w0 : (region == 1) ? w1 : (region == 2) ? w2 : w3;
  f32x4 a = *(const f32x4*)(s + off);
  f32x4 b = *(const f32x4*)(s + off + 4);
  int row = off >> 9;
  int k   = off & 511;                             // multiple of 8
  int ks  = (region < 3) ? ((k & ~63) | ((k & 63) ^ ((row & 7) << 3))) : k;
  *(half8*)(out + region * 262144 + row*512 + ks) = cvt8(a, b);
}

// ---------------- mask dtype detection ----------------
__global__ void detect_mask_kernel(const uint32* __restrict__ m, int* __restrict__ flag){
  __shared__ int s_gt1, s_bgt1;
  if (threadIdx.x == 0){ s_gt1 = 0; s_bgt1 = 0; }
  __syncthreads();
  int gt1 = 0, bgt1 = 0;
  for (int i = threadIdx.x; i < 4096; i += 256){
    uint32 w = m[i];
    if (w > 1u) gt1 = 1;
    if (((w)&0xffu) > 1u || ((w>>8)&0xffu) > 1u || ((w>>16)&0xffu) > 1u || ((w>>24)&0xffu) > 1u) bgt1 = 1;
  }
  if (gt1)  atomicOr(&s_gt1, 1);
  if (bgt1) atomicOr(&s_bgt1, 1);
  __syncthreads();
  if (threadIdx.x == 0) *flag = s_gt1 ? (s_bgt1 ? 2 : 1) : 0;
}

__global__ void pack_mask_kernel(const uint32* __restrict__ m, const int* __restrict__ flag,
                                 uint32* __restrict__ bits){
  const int w = blockIdx.x * 256 + threadIdx.x;   // 524288 words total
  const int f = *flag;
  uint32 out = 0u;
  if (f == 1){
    #pragma unroll
    for (int i = 0; i < 2; i++){
      u32x4 v = *(const u32x4*)(m + (size_t)w*8 + i*4);
      #pragma unroll
      for (int j = 0; j < 4; j++){
        uint32 x = v[j];
        if (x & 0x000000ffu) out |= 1u << (i*16 + j*4 + 0);
        if (x & 0x0000ff00u) out |= 1u << (i*16 + j*4 + 1);
        if (x & 0x00ff0000u) out |= 1u << (i*16 + j*4 + 2);
        if (x & 0xff000000u) out |= 1u << (i*16 + j*4 + 3);
      }
    }
  } else {
    #pragma unroll
    for (int i = 0; i < 8; i++){
      u32x4 v = *(const u32x4*)(m + (size_t)w*32 + i*4);
      if (v[0]) out |= 1u << (i*4 + 0);
      if (v[1]) out |= 1u << (i*4 + 1);
      if (v[2]) out |= 1u << (i*4 + 2);
      if (v[3]) out |= 1u << (i*4 + 3);
    }
  }
  bits[w] = out;
}

// ---------------- projection GEMM (swapped): C(arow,n) = Act(arow,:)·W(n,:)  ----------------
// A = W (512x512 f16, PRE-SWIZZLED rows) via GLD16, DOUBLE-BUFFERED (next tile issued pre-MFMA).
// B = Act f32: T14 issue-early (pre-MFMA) / write-late (post-barrier) into single swz LDS buf.
// MFMA: out[row = n (4 consec per lane)][col = arow (lrow)].
// MODE 0: Qb/Kb store f16 at ((b*8+h)*ROWS + rr)*64 + d, packed 8B (h=n>>6, d=n&63)
// MODE 1: Vt  store f16 at b*524288 + n*1024 + s (2B scatter)
template<int MODE>
__global__ __launch_bounds__(256) void gemm_proj(
    const u16* __restrict__ Wsz, const float* __restrict__ Act,
    u16* __restrict__ Cp, int rshift, float scale)
{
  __shared__ __align__(16) u16 As[2][128*64];
  __shared__ __align__(16) u16 Bs[128*64];
  const int tid  = threadIdx.x;
  const int lane = tid & 63;
  const int wv   = tid >> 6;
  const int lrow = lane & 15, khi = lane >> 4;
  const int wm   = wv >> 1,  wn  = wv & 1;

  const int nwg = gridDim.x;
  const int bid = blockIdx.x;
  const int l   = (bid & 7) * (nwg >> 3) + (bid >> 3);   // XCD chunk (nwg % 8 == 0)
  const int by  = l & 3;            // W-row tile (4 by's of one act-tile adjacent -> L2 reuse)
  const long bxL = l >> 2;          // act-row tile

  const long gm0 = (long)by * 128;  // W rows
  const long gn0 = bxL * 128;       // act rows
  const int  srow = tid >> 1, scb = (tid & 1) * 32;
  const float* bp0 = Act + (gn0 + srow)*512 + scb;

  f32x4 breg[8];
  // prologue: stage K-step 0 (A into As[0], B via regs into Bs)
  #pragma unroll
  for (int j = 0; j < 4; j++){
    int row = j*32 + (tid >> 3);
    GLD16(&As[0][j*2048 + tid*8], Wsz + (gm0 + row)*512 + (tid & 7)*8);
  }
  #pragma unroll
  for (int i = 0; i < 8; i++) breg[i] = *(const f32x4*)(bp0 + i*4);
  #pragma unroll
  for (int i = 0; i < 4; i++)
    *(half8*)&Bs[swz(srow, scb + i*8)] = cvt8(breg[2*i], breg[2*i+1]);
  __syncthreads();

  f32x4 acc[4][4];
  #pragma unroll
  for (int i = 0; i < 4; i++)
    #pragma unroll
    for (int j = 0; j < 4; j++) acc[i][j] = (f32x4){0.f,0.f,0.f,0.f};

  #pragma unroll 1
  for (int t = 0; t < 8; t++){
    const int kk = t * 64;
    const u16* Acur = &As[t & 1][0];
    // issue next-step loads BEFORE the MFMA cluster (latency hides under compute)
    if (t < 7){
      u16* Anx = &As[(t + 1) & 1][0];
      #pragma unroll
      for (int j = 0; j < 4; j++){
        int row = j*32 + (tid >> 3);
        GLD16(&Anx[j*2048 + tid*8], Wsz + (gm0 + row)*512 + kk + 64 + (tid & 7)*8);
      }
      #pragma unroll
      for (int i = 0; i < 8; i++) breg[i] = *(const f32x4*)(bp0 + kk + 64 + i*4);
    }

    half8 af[4][2], bf[4][2];
    #pragma unroll
    for (int mi = 0; mi < 4; mi++){
      const int r_ = wm*64 + mi*16 + lrow;
      af[mi][0] = *(const half8*)&Acur[swz(r_, khi*8)];
      af[mi][1] = *(const half8*)&Acur[swz(r_, khi*8 + 32)];
    }
    #pragma unroll
    for (int ni = 0; ni < 4; ni++){
      const int r_ = wn*64 + ni*16 + lrow;
      bf[ni][0] = *(const half8*)&Bs[swz(r_, khi*8)];
      bf[ni][1] = *(const half8*)&Bs[swz(r_, khi*8 + 32)];
    }
    __builtin_amdgcn_s_setprio(1);
    #pragma unroll
    for (int mi = 0; mi < 4; mi++)
      #pragma unroll
      for (int ni = 0; ni < 4; ni++){
        acc[mi][ni] = mfma16(af[mi][0], bf[ni][0], acc[mi][ni]);
        acc[mi][ni] = mfma16(af[mi][1], bf[ni][1], acc[mi][ni]);
      }
    __builtin_amdgcn_s_setprio(0);
    __syncthreads();               // Bs readers done (also drains in-flight GLD16/breg)
    if (t < 7){
      #pragma unroll
      for (int i = 0; i < 4; i++)
        *(half8*)&Bs[swz(srow, scb + i*8)] = cvt8(breg[2*i], breg[2*i+1]);
      __syncthreads();             // Bs(t+1) visible before next iteration's reads
    }
  }

  #pragma unroll
  for (int mi = 0; mi < 4; mi++)
    #pragma unroll
    for (int ni = 0; ni < 4; ni++){
      f32x4 v = acc[mi][ni];
      const long arow = gn0 + wn*64 + ni*16 + lrow;
      if (MODE == 0){
        const int h  = (int)(gm0 >> 6) + wm;
        const int d0 = mi*16 + khi*4;
        const long b  = arow >> rshift;
        const long rr = arow & ((1L << rshift) - 1);
        u32x2 p;
        p.x = pk16(v[0]*scale, v[1]*scale);
        p.y = pk16(v[2]*scale, v[3]*scale);
        *(u32x2*)&Cp[(((b*8 + h) << rshift) + rr)*64 + d0] = p;
      } else {
        const long n = gm0 + wm*64 + mi*16 + khi*4;
        const long b = arow >> 10, s = arow & 1023;
        #pragma unroll
        for (int r = 0; r < 4; r++)
          Cp[b*524288 + (n + r)*1024 + s] = f2h_bits(v[r]);
      }
    }
}

// ---------------- out-projection GEMM: C = A(MxK f16)·B(NxK f16)^T + bias, f32 out --------
__global__ __launch_bounds__(256) void gemm_out(
    const u16* __restrict__ Ap, const u16* __restrict__ Bp,
    float* __restrict__ Cp, const float* __restrict__ bias)
{
  __shared__ __align__(16) u16 As[128*64];
  __shared__ __align__(16) u16 Bs[128*64];
  const int tid  = threadIdx.x;
  const int lane = tid & 63;
  const int wv   = tid >> 6;
  const int lrow = lane & 15, khi = lane >> 4;
  const int wm   = wv >> 1,  wn  = wv & 1;

  int bx = blockIdx.x, by = blockIdx.y;
  {
    const int nbx = gridDim.x;
    const int nwg = nbx * gridDim.y;
    const int bid = by * nbx + bx;
    const int l = (bid & 7) * (nwg >> 3) + (bid >> 3);
    by = l / nbx; bx = l - by * nbx;
  }
  const long gm0 = (long)by * 128;
  const long gn0 = (long)bx * 128;

  f32x4 acc[4][4];
  #pragma unroll
  for (int i = 0; i < 4; i++)
    #pragma unroll
    for (int j = 0; j < 4; j++) acc[i][j] = (f32x4){0.f,0.f,0.f,0.f};

  #pragma unroll 1
  for (int kk = 0; kk < 512; kk += 64){
    if (kk) __syncthreads();
    #pragma unroll
    for (int j = 0; j < 4; j++){
      int row = j*32 + (tid >> 3);
      GLD16(&As[j*2048 + tid*8], Ap + (gm0 + row)*512 + kk + (tid & 7)*8);
      GLD16(&Bs[j*2048 + tid*8], Bp + (gn0 + row)*512 + kk + (tid & 7)*8);
    }
    __syncthreads();

    half8 af[4][2], bf[4][2];
    #pragma unroll
    for (int mi = 0; mi < 4; mi++){
      const u16* p = &As[(wm*64 + mi*16 + lrow)*64 + khi*8];
      af[mi][0] = *(const half8*)p;
      af[mi][1] = *(const half8*)(p + 32);
    }
    #pragma unroll
    for (int ni = 0; ni < 4; ni++){
      const u16* p = &Bs[(wn*64 + ni*16 + lrow)*64 + khi*8];
      bf[ni][0] = *(const half8*)p;
      bf[ni][1] = *(const half8*)(p + 32);
    }
    #pragma unroll
    for (int mi = 0; mi < 4; mi++)
      #pragma unroll
      for (int ni = 0; ni < 4; ni++){
        acc[mi][ni] = mfma16(af[mi][0], bf[ni][0], acc[mi][ni]);
        acc[mi][ni] = mfma16(af[mi][1], bf[ni][1], acc[mi][ni]);
      }
  }

  #pragma unroll
  for (int mi = 0; mi < 4; mi++)
    #pragma unroll
    for (int ni = 0; ni < 4; ni++)
      #pragma unroll
      for (int r = 0; r < 4; r++){
        long gm = gm0 + wm*64 + mi*16 + khi*4 + r;
        long gn = gn0 + wn*64 + ni*16 + lrow;
        Cp[gm*512 + gn] = acc[mi][ni][r] + bias[gn];
      }
}

// ---------------- flash attention (swapped QK^T, reg softmax, T14 prefetch) ----------------
__global__ __launch_bounds__(256) void attn_kernel(
    const u16* __restrict__ Qb, const u16* __restrict__ Kb,
    const u16* __restrict__ Vtb, const uint32* __restrict__ bits,
    u16* __restrict__ Ctx)
{
  __shared__ __align__(16) u16 Ks[64*64];   // K tile (also Q staging pre-loop)
  __shared__ __align__(16) u16 Vs[64*64];   // Vt tile (rows=d, cols=s)

  const int tid  = threadIdx.x;
  const int lane = tid & 63;
  const int wv   = tid >> 6;
  const int lrow = lane & 15, khi = lane >> 4;

  const int bidx = blockIdx.x;
  const int logical = (bidx & 7) * 256 + (bidx >> 3);   // XCD swizzle
  const int bh = logical >> 3;
  const int p0 = (logical & 7) * 64;
  const int bb = bh >> 3;

  const u16* qp = Qb  + (size_t)bh * (P_*64) + (size_t)p0 * 64;
  const u16* kp = Kb  + (size_t)bh * (S_*64);
  const u16* vp = Vtb + (size_t)bh * (D_*S_);
  const int srow = tid >> 2, scb = (tid & 3) * 16;
  const size_t mbase = (size_t)(bb*P_ + p0 + wv*16 + lrow) * (S_/32);

  // T14: prefetch tile 0 K/V + mask into regs
  half8 kr0 = *(const half8*)(kp + (size_t)srow*64 + scb);
  half8 kr1 = *(const half8*)(kp + (size_t)srow*64 + scb + 8);
  half8 vr0 = *(const half8*)(vp + (size_t)srow*S_ + scb);
  half8 vr1 = *(const half8*)(vp + (size_t)srow*S_ + scb + 8);
  uint32 mw0 = bits[mbase], mw1 = bits[mbase + 1];

  // stage Q through Ks; read per-wave Q frags (q = wv*16+lrow); Q is pre-scaled by 0.125*log2e
  {
    const u16* src = qp + (size_t)srow*64 + scb;
    *(half8*)&Ks[swz(srow, scb)]     = *(const half8*)src;
    *(half8*)&Ks[swz(srow, scb + 8)] = *(const half8*)(src + 8);
  }
  __syncthreads();
  half8 q_lo = *(const half8*)&Ks[swz(wv*16 + lrow, khi*8)];
  half8 q_hi = *(const half8*)&Ks[swz(wv*16 + lrow, khi*8 + 32)];

  f32x4 accO[4];   // accO[dsub][r] = O^T[d=dsub*16+khi*4+r][q=lrow]
  #pragma unroll
  for (int i = 0; i < 4; i++) accO[i] = (f32x4){0.f,0.f,0.f,0.f};
  float mst = -1e30f, lst = 0.f;

  const int srcA = (lrow + 16*((2*khi)    & 3)) << 2;  // bpermute byte addrs
  const int srcB = (lrow + 16*((2*khi + 1)& 3)) << 2;
  const bool hiH = khi >= 2;

  #pragma unroll 1
  for (int t = 0; t < 16; t++){
    __syncthreads();      // prev tile readers / Q frag reads done
    *(half8*)&Ks[swz(srow, scb)]     = kr0;
    *(half8*)&Ks[swz(srow, scb + 8)] = kr1;
    *(half8*)&Vs[swz(srow, scb)]     = vr0;
    *(half8*)&Vs[swz(srow, scb + 8)] = vr1;
    __syncthreads();
    const uint32 cm0 = mw0, cm1 = mw1;
    if (t < 15){          // issue next-tile loads; latency hides under compute below
      const u16* kn = kp + (size_t)(t + 1)*4096 + (size_t)srow*64 + scb;
      kr0 = *(const half8*)kn; kr1 = *(const half8*)(kn + 8);
      const u16* vn = vp + (size_t)srow*S_ + (t + 1)*64 + scb;
      vr0 = *(const half8*)vn; vr1 = *(const half8*)(vn + 8);
      mw0 = bits[mbase + (t + 1)*2]; mw1 = bits[mbase + (t + 1)*2 + 1];
    }

    // S^T = K . Q^T : sc[ssub][r] = S[s = ssub*16 + khi*4 + r][q = lrow] (exp2 domain)
    f32x4 sc[4];
    __builtin_amdgcn_s_setprio(1);
    #pragma unroll
    for (int ssub = 0; ssub < 4; ssub++){
      const int rr = ssub*16 + lrow;
      half8 k_lo = *(const half8*)&Ks[swz(rr, khi*8)];
      half8 k_hi = *(const half8*)&Ks[swz(rr, khi*8 + 32)];
      f32x4 c = (f32x4){0.f,0.f,0.f,0.f};
      c = mfma16(k_lo, q_lo, c);
      c = mfma16(k_hi, q_hi, c);
      sc[ssub] = c;
    }
    __builtin_amdgcn_s_setprio(0);

    // mask; row(q)-reduce in-lane + 2 shfl
    float mx = -1e30f;
    #pragma unroll
    for (int ssub = 0; ssub < 4; ssub++){
      const uint32 mw = (ssub < 2) ? cm0 : cm1;
      #pragma unroll
      for (int r = 0; r < 4; r++){
        const int s = ssub*16 + khi*4 + r;
        float v = sc[ssub][r];
        if ((mw >> (s & 31)) & 1u) v = -1e30f;
        sc[ssub][r] = v;
        mx = fmaxf(mx, v);
      }
    }
    mx = fmaxf(mx, __shfl_xor(mx, 16));
    mx = fmaxf(mx, __shfl_xor(mx, 32));
    // T13 defer-max: only rescale when tile max grew past THR=8 (P bounded by 2^8, f16-safe)
    if (__any(mx - mst > 8.f)){
      const float mnew = fmaxf(mst, mx);
      const float fac = __builtin_amdgcn_exp2f(mst - mnew);
      lst *= fac;
      #pragma unroll
      for (int d = 0; d < 4; d++){
        f32x4 a = accO[d];
        a[0] *= fac; a[1] *= fac; a[2] *= fac; a[3] *= fac;
        accO[d] = a;
      }
      mst = mnew;
    }
    float ts = 0.f;
    #pragma unroll
    for (int ssub = 0; ssub < 4; ssub++)
      #pragma unroll
      for (int r = 0; r < 4; r++){
        float p = __builtin_amdgcn_exp2f(sc[ssub][r] - mst);
        sc[ssub][r] = p;
        ts += p;
      }
    ts += __shfl_xor(ts, 16);
    ts += __shfl_xor(ts, 32);
    lst += ts;

    // pack P rows to f16; redistribute to PV B-frag layout via bpermute
    uint32 w00 = pk16(sc[0][0], sc[0][1]), w01 = pk16(sc[0][2], sc[0][3]);
    uint32 w10 = pk16(sc[1][0], sc[1][1]), w11 = pk16(sc[1][2], sc[1][3]);
    uint32 w20 = pk16(sc[2][0], sc[2][1]), w21 = pk16(sc[2][2], sc[2][3]);
    uint32 w30 = pk16(sc[3][0], sc[3][1]), w31 = pk16(sc[3][2], sc[3][3]);

    union { half8 h; uint32 u[4]; } plo, phi;
    {
      uint32 t0, t1;
      t0 = __builtin_amdgcn_ds_bpermute(srcA, (int)w00);
      t1 = __builtin_amdgcn_ds_bpermute(srcA, (int)w10);
      plo.u[0] = hiH ? t1 : t0;
      t0 = __builtin_amdgcn_ds_bpermute(srcA, (int)w01);
      t1 = __builtin_amdgcn_ds_bpermute(srcA, (int)w11);
      plo.u[1] = hiH ? t1 : t0;
      t0 = __builtin_amdgcn_ds_bpermute(srcB, (int)w00);
      t1 = __builtin_amdgcn_ds_bpermute(srcB, (int)w10);
      plo.u[2] = hiH ? t1 : t0;
      t0 = __builtin_amdgcn_ds_bpermute(srcB, (int)w01);
      t1 = __builtin_amdgcn_ds_bpermute(srcB, (int)w11);
      plo.u[3] = hiH ? t1 : t0;
      t0 = __builtin_amdgcn_ds_bpermute(srcA, (int)w20);
      t1 = __builtin_amdgcn_ds_bpermute(srcA, (int)w30);
      phi.u[0] = hiH ? t1 : t0;
      t0 = __builtin_amdgcn_ds_bpermute(srcA, (int)w21);
      t1 = __builtin_amdgcn_ds_bpermute(srcA, (int)w31);
      phi.u[1] = hiH ? t1 : t0;
      t0 = __builtin_amdgcn_ds_bpermute(srcB, (int)w20);
      t1 = __builtin_amdgcn_ds_bpermute(srcB, (int)w30);
      phi.u[2] = hiH ? t1 : t0;
      t0 = __builtin_amdgcn_ds_bpermute(srcB, (int)w21);
      t1 = __builtin_amdgcn_ds_bpermute(srcB, (int)w31);
      phi.u[3] = hiH ? t1 : t0;
    }

    // O^T += V^T . P^T
    __builtin_amdgcn_s_setprio(1);
    #pragma unroll
    for (int dsub = 0; dsub < 4; dsub++){
      const int rr = dsub*16 + lrow;
      half8 v_lo = *(const half8*)&Vs[swz(rr, khi*8)];
      half8 v_hi = *(const half8*)&Vs[swz(rr, khi*8 + 32)];
      accO[dsub] = mfma16(v_lo, plo.h, accO[dsub]);
      accO[dsub] = mfma16(v_hi, phi.h, accO[dsub]);
    }
    __builtin_amdgcn_s_setprio(0);
  }

  // epilogue: lane holds q = lrow, d = dsub*16 + khi*4 + r -> packed 8B stores
  const int hh = bh & 7;
  const float inv = __builtin_amdgcn_rcpf(lst);
  const size_t base = (size_t)(bb*P_ + p0 + wv*16 + lrow) * E_ + hh*64 + khi*4;
  #pragma unroll
  for (int dsub = 0; dsub < 4; dsub++){
    u32x2 pkd;
    pkd.x = pk16(accO[dsub][0] * inv, accO[dsub][1] * inv);
    pkd.y = pk16(accO[dsub][2] * inv, accO[dsub][3] * inv);
    *(u32x2*)&Ctx[base + dsub*16] = pkd;
  }
}

extern "C" void kernel_launch(void* const* d_in, const int* in_sizes, int n_in,
                              void* d_out, int out_size, void* d_ws, size_t ws_size,
                              hipStream_t stream)
{
  const float* query = (const float*)d_in[0];
  const float* key   = (const float*)d_in[1];
  const float* value = (const float*)d_in[2];
  const void*  mask  = d_in[3];
  const float* Wq = (const float*)d_in[4];
  const float* Wk = (const float*)d_in[5];
  const float* Wv = (const float*)d_in[6];
  const float* Wo = (const float*)d_in[7];
  const float* bo = (const float*)d_in[8];

  // ws layout (98 MiB, no overlaps): Qb[0,16) Kb[16,48) Vtb[48,80) Ctx[80,96) W4h[96,98)
  // bits (2 MiB) + flag live in d_out scratch (overwritten by final GEMM).
  char* ws = (char*)d_ws;
  u16*    Qb   = (u16*)(ws);
  u16*    Kb   = (u16*)(ws + (16u << 20));
  u16*    Vtb  = (u16*)(ws + (48u << 20));
  u16*    Ctx  = (u16*)(ws + (80u << 20));
  u16*    W4h  = (u16*)(ws + (96u << 20));
  uint32* bits = (uint32*)d_out;
  int*    flag = (int*)((char*)d_out + (2u << 20));

  const float SCLQ = 0.125f * 1.44269504f;   // fold softmax scale * log2(e) into Q

  cvt_w_kernel<<<512, 256, 0, stream>>>(Wq, Wk, Wv, Wo, W4h);
  detect_mask_kernel<<<1, 256, 0, stream>>>((const uint32*)mask, flag);
  pack_mask_kernel<<<2048, 256, 0, stream>>>((const uint32*)mask, flag, bits);
  // Q: act rows 16384 (rshift=9), pre-scaled
  gemm_proj<0><<<512, 256, 0, stream>>>(W4h, query, Qb, 9, SCLQ);
  // K: act rows 32768 (rshift=10)
  gemm_proj<0><<<1024, 256, 0, stream>>>(W4h + 262144, key, Kb, 10, 1.0f);
  // Vt: act rows 32768
  gemm_proj<1><<<1024, 256, 0, stream>>>(W4h + 524288, value, Vtb, 0, 1.0f);
  attn_kernel<<<2048, 256, 0, stream>>>(Qb, Kb, Vtb, bits, Ctx);
  // out = ctx @ Wo^T + bo
  gemm_out<<<dim3(4, 128), 256, 0, stream>>>(Ctx, W4h + 786432, (float*)d_out, bo);
}